// Round 6
// baseline (461.739 us; speedup 1.0000x reference)
//
#include <hip/hip_runtime.h>
#include <hip/hip_bf16.h>
#include <math.h>

// B=4, T=2048, D=1024, H=16, DH=64.  fp32 in / fp32 out, bf16 MFMA internal.
// out = softmax_causal((xWq)(xWk)^T / 8) (xWv) @ Wout

#define Bb 4
#define Tt 2048
#define Dd 1024
#define Hh 16
#define DH 64
#define Mrows (Bb*Tt)          // 8192
#define NEGBIG (-1.0e30f)

typedef unsigned short u16;
typedef __attribute__((ext_vector_type(8))) short bf16x8;
typedef __attribute__((ext_vector_type(4))) float f32x4;

__device__ __forceinline__ float bf2f(u16 u) {
    union { unsigned int i; float f; } v; v.i = ((unsigned int)u) << 16; return v.f;
}
__device__ __forceinline__ u16 f2bf(float f) {
    union { float f; unsigned int i; } v; v.f = f;
    unsigned int x = v.i;
    return (u16)((x + 0x7fffu + ((x >> 16) & 1u)) >> 16);      // RNE
}

__device__ __forceinline__ float exp2_(float x) {
#if __has_builtin(__builtin_amdgcn_exp2f)
    return __builtin_amdgcn_exp2f(x);      // v_exp_f32: D = 2^S0
#else
    return __expf(x * 0.69314718056f);
#endif
}

typedef __attribute__((address_space(1))) const void glob_cv;
typedef __attribute__((address_space(3))) void lds_v;
__device__ __forceinline__ void gl2lds16(const void* g, void* l) {
    __builtin_amdgcn_global_load_lds((glob_cv*)g, (lds_v*)l, 16, 0, 0);
}

// ---------------------------------------------------------------------------
// fp32 -> bf16 straight convert (x).  8 elems/thread, 16B stores.
// ---------------------------------------------------------------------------
__global__ __launch_bounds__(256) void convert_x(const float* __restrict__ src,
                                                 u16* __restrict__ dst) {
    const long i = ((long)blockIdx.x * 256 + threadIdx.x) * 8;
    float4 f0 = *(const float4*)(src + i);
    float4 f1 = *(const float4*)(src + i + 4);
    union { u16 u[8]; uint4 v; } o;
    o.u[0] = f2bf(f0.x); o.u[1] = f2bf(f0.y); o.u[2] = f2bf(f0.z); o.u[3] = f2bf(f0.w);
    o.u[4] = f2bf(f1.x); o.u[5] = f2bf(f1.y); o.u[6] = f2bf(f1.z); o.u[7] = f2bf(f1.w);
    *(uint4*)(dst + i) = o.v;
}

// ---------------------------------------------------------------------------
// fp32 W[K][N] -> bf16 Wt[N][K]  (transpose via padded LDS tile, coalesced).
// ---------------------------------------------------------------------------
__global__ __launch_bounds__(256) void convert_transpose_w(const float* __restrict__ W,
                                                           u16* __restrict__ Wt,
                                                           int N, int K) {
    __shared__ u16 tile[64][65];
    const int n0 = blockIdx.x * 64, k0 = blockIdx.y * 64;
    const int c = threadIdx.x & 63, r4 = threadIdx.x >> 6;
    #pragma unroll
    for (int p = 0; p < 16; ++p) {
        const int r = p * 4 + r4;
        tile[r][c] = f2bf(W[(size_t)(k0 + r) * N + n0 + c]);
    }
    __syncthreads();
    #pragma unroll
    for (int p = 0; p < 16; ++p) {
        const int r = p * 4 + r4;     // n index
        Wt[(size_t)(n0 + r) * K + k0 + c] = tile[c][r];
    }
}

// ---------------------------------------------------------------------------
// V [bh][t][dh] -> Vt [bh][dh][t]
// ---------------------------------------------------------------------------
__global__ __launch_bounds__(256) void transpose_v(const u16* __restrict__ V,
                                                   u16* __restrict__ Vt) {
    __shared__ u16 tile[64][65];
    const int t0 = blockIdx.x * 64, bh = blockIdx.y;
    const size_t ib = (size_t)bh * Tt * DH, ob = (size_t)bh * DH * Tt;
    const int c = threadIdx.x & 63, r4 = threadIdx.x >> 6;
    #pragma unroll
    for (int p = 0; p < 16; ++p) {
        const int r = p * 4 + r4;
        tile[r][c] = V[ib + (size_t)(t0 + r) * DH + c];
    }
    __syncthreads();
    #pragma unroll
    for (int p = 0; p < 16; ++p) {
        const int r = p * 4 + r4;     // dh
        Vt[ob + (size_t)r * Tt + t0 + c] = tile[c][r];
    }
}

// ---------------------------------------------------------------------------
// MFMA GEMM: C[M][N] = A[M][K] * Bt[N][K]^T, K=1024, BK=32, 128x128 tile,
// 4 waves (2x2), each 4x4 MFMA 16x16x32 tiles.  LDS layout [kblk][row][8].
// MODE 0: scatter to Q(xlog2e/8)/K/V (B,H,T,DH) bf16.  MODE 1: fp32 out.
// ---------------------------------------------------------------------------
template <int MODE>
__global__ __launch_bounds__(256) void gemm_mfma(const u16* __restrict__ A,
                                                 const u16* __restrict__ Bt,
                                                 u16* __restrict__ Qo,
                                                 u16* __restrict__ Ko,
                                                 u16* __restrict__ Vo,
                                                 float* __restrict__ Out) {
    __shared__ u16 As[4 * 128 * 8];      // [qb 0..3][row 0..127][8]
    __shared__ u16 Bs[4 * 128 * 8];
    const int tid  = threadIdx.x;
    const int lane = tid & 63, w = tid >> 6;
    const int ml   = lane & 15, q = lane >> 4;     // fragment row/col & quad
    const int wm   = w >> 1, wn = w & 1;
    const int m0 = blockIdx.y * 128, n0 = blockIdx.x * 128;

    f32x4 acc[4][4];
    #pragma unroll
    for (int i = 0; i < 4; ++i)
        #pragma unroll
        for (int j = 0; j < 4; ++j) acc[i][j] = (f32x4){0.f, 0.f, 0.f, 0.f};

    for (int k0 = 0; k0 < Dd; k0 += 32) {
        __syncthreads();
        #pragma unroll
        for (int it = 0; it < 2; ++it) {
            const int c = it * 256 + tid;          // chunk 0..511
            const int row = c & 127, qb = c >> 7;  // LDS off = c*16
            gl2lds16(A  + (size_t)(m0 + row) * Dd + k0 + qb * 8, (char*)As + c * 16);
            gl2lds16(Bt + (size_t)(n0 + row) * Dd + k0 + qb * 8, (char*)Bs + c * 16);
        }
        __syncthreads();

        bf16x8 af[4], bfr[4];
        #pragma unroll
        for (int i = 0; i < 4; ++i)
            af[i] = *(const bf16x8*)((const char*)As + (q * 128 + wm * 64 + i * 16 + ml) * 16);
        #pragma unroll
        for (int j = 0; j < 4; ++j)
            bfr[j] = *(const bf16x8*)((const char*)Bs + (q * 128 + wn * 64 + j * 16 + ml) * 16);
        #pragma unroll
        for (int i = 0; i < 4; ++i)
            #pragma unroll
            for (int j = 0; j < 4; ++j)
                acc[i][j] = __builtin_amdgcn_mfma_f32_16x16x32_bf16(af[i], bfr[j], acc[i][j], 0, 0, 0);
    }

    // epilogue: C/D layout col=lane&15, row=quad*4+reg
    #pragma unroll
    for (int i = 0; i < 4; ++i) {
        #pragma unroll
        for (int j = 0; j < 4; ++j) {
            #pragma unroll
            for (int r = 0; r < 4; ++r) {
                const int m = m0 + wm * 64 + i * 16 + q * 4 + r;
                const int n = n0 + wn * 64 + j * 16 + ml;
                if (MODE == 0) {
                    const int bb = m >> 11, t = m & 2047;
                    const int s = n >> 10, rem = n & 1023, h = rem >> 6, dh = rem & 63;
                    float v = acc[i][j][r];
                    // Q: fold 1/sqrt(DH) * log2(e) so attention can use v_exp_f32
                    // (base-2) directly; applied in fp32 before bf16 rounding.
                    if (s == 0) v *= 0.125f * 1.44269504089f;
                    u16* dst = (s == 0) ? Qo : (s == 1 ? Ko : Vo);
                    dst[(((size_t)(bb * Hh + h)) * Tt + t) * DH + dh] = f2bf(v);
                } else {
                    Out[(size_t)m * Dd + n] = acc[i][j][r];
                }
            }
        }
    }
}

// ---------------------------------------------------------------------------
// MFMA flash attention, S^T formulation.
// Block: 128 Q-rows, 4 waves; wave owns 32 queries (2 blocks of 16).
// Q fragments live in REGISTERS (loop-invariant) -> LDS 49KB -> 3 blocks/CU.
// Diagonal 128-block: wave-uniform tile skipping (ktlim/slim) removes
// fully-masked S-MFMAs, exp2 calls, and PV MFMAs.
// ---------------------------------------------------------------------------
__global__ __launch_bounds__(256) void attn_mfma(const u16* __restrict__ Q,
                                                 const u16* __restrict__ K,
                                                 const u16* __restrict__ Vt,
                                                 u16* __restrict__ AO) {
    __shared__ u16 Ks[8 * 128 * 8];      // [dhb 0..7][key  0..127][8]   16 KB
    __shared__ u16 Vs[16 * 64 * 8];      // [kb 0..15][dh 0..63][8]      16 KB
    __shared__ u16 Ps[4][16 * 136];      // per-wave [query 16][128+8 pad] 17 KB

    const int tid  = threadIdx.x;
    const int lane = tid & 63, w = tid >> 6;
    const int nl   = lane & 15, q = lane >> 4;
    const int q0 = blockIdx.x * 128;
    const int bh = blockIdx.y, b = bh >> 4, h = bh & 15;
    const size_t kbase = (size_t)bh * Tt * DH;
    const size_t vbase = (size_t)bh * DH * Tt;

    // Q fragments in registers: qf[qb][s] = Q[qrow][(s*4+q)*8 .. +7]
    bf16x8 qf[2][2];
    #pragma unroll
    for (int qb = 0; qb < 2; ++qb)
        #pragma unroll
        for (int s = 0; s < 2; ++s)
            qf[qb][s] = *(const bf16x8*)(Q + kbase +
                    (size_t)(q0 + w * 32 + qb * 16 + nl) * DH + (s * 4 + q) * 8);

    float m_i[2] = {NEGBIG, NEGBIG};
    float l_i[2] = {0.f, 0.f};
    f32x4 accO[2][4];
    #pragma unroll
    for (int qb = 0; qb < 2; ++qb)
        #pragma unroll
        for (int dt = 0; dt < 4; ++dt) accO[qb][dt] = (f32x4){0.f, 0.f, 0.f, 0.f};

    for (int j0 = 0; j0 <= q0; j0 += 128) {
        __syncthreads();
        #pragma unroll
        for (int it = 0; it < 4; ++it) {
            const int c = it * 256 + tid;
            gl2lds16(K + kbase + (size_t)(j0 + (c & 127)) * DH + (c >> 7) * 8,
                     (char*)Ks + c * 16);
        }
        #pragma unroll
        for (int it = 0; it < 4; ++it) {
            const int c = it * 256 + tid;
            gl2lds16(Vt + vbase + (size_t)(c & 63) * Tt + j0 + (c >> 6) * 8,
                     (char*)Vs + c * 16);
        }
        __syncthreads();

        const bool diag = (j0 == q0);

        #pragma unroll
        for (int qb = 0; qb < 2; ++qb) {
            const int qrow = w * 32 + qb * 16 + nl;    // block-local query
            const int ktlim = diag ? (w * 2 + qb) : 7; // wave-uniform
            const int slim  = diag ? w : 3;            // wave-uniform

            // S^T: lane holds keys (kt*16 + q*4 + r) for query qrow
            f32x4 accst[8];
            #pragma unroll
            for (int kt = 0; kt < 8; ++kt) {
                if (kt <= ktlim) {
                    accst[kt] = (f32x4){0.f, 0.f, 0.f, 0.f};
                    #pragma unroll
                    for (int s = 0; s < 2; ++s) {
                        bf16x8 ak = *(const bf16x8*)((const char*)Ks +
                                ((s * 4 + q) * 128 + kt * 16 + nl) * 16);
                        accst[kt] = __builtin_amdgcn_mfma_f32_16x16x32_bf16(
                                ak, qf[qb][s], accst[kt], 0, 0, 0);
                    }
                }
            }

            // causal mask (partial tiles of the diagonal block)
            if (diag) {
                #pragma unroll
                for (int kt = 0; kt < 8; ++kt)
                    if (kt <= ktlim)
                        #pragma unroll
                        for (int r = 0; r < 4; ++r)
                            if (kt * 16 + q * 4 + r > qrow) accst[kt][r] = NEGBIG;
            }

            // stats: in-register reduce + 2 shuffles
            float mx = NEGBIG;
            #pragma unroll
            for (int kt = 0; kt < 8; ++kt) {
                if (kt <= ktlim) {
                    float a0 = fmaxf(accst[kt][0], accst[kt][1]);
                    float a1 = fmaxf(accst[kt][2], accst[kt][3]);
                    mx = fmaxf(mx, fmaxf(a0, a1));
                }
            }
            mx = fmaxf(mx, __shfl_xor(mx, 16, 64));
            mx = fmaxf(mx, __shfl_xor(mx, 32, 64));
            const float nm    = fmaxf(m_i[qb], mx);
            const float alpha = exp2_(m_i[qb] - nm);
            m_i[qb] = nm;

            float rs = 0.f;
            #pragma unroll
            for (int kt = 0; kt < 8; ++kt) {
                if (kt <= ktlim) {
                    union { u16 u[4]; uint2 v; } pk;
                    #pragma unroll
                    for (int r = 0; r < 4; ++r) {
                        const float p = exp2_(accst[kt][r] - nm);
                        rs += p;
                        pk.u[r] = f2bf(p);
                    }
                    *(uint2*)((char*)Ps[w] + nl * 272 + kt * 32 + q * 8) = pk.v;
                } else if (kt <= 2 * slim + 1) {
                    // zero-fill rows PV will still consume
                    *(uint2*)((char*)Ps[w] + nl * 272 + kt * 32 + q * 8) = (uint2){0u, 0u};
                }
            }
            rs += __shfl_xor(rs, 16, 64);
            rs += __shfl_xor(rs, 32, 64);
            l_i[qb] = l_i[qb] * alpha + rs;

            // rescale O^T (query on lane -> in-lane alpha)
            #pragma unroll
            for (int dt = 0; dt < 4; ++dt)
                #pragma unroll
                for (int r = 0; r < 4; ++r) accO[qb][dt][r] *= alpha;

            // O^T += V^T · P^T   (a = Vt rows, b = Ps rows)
            #pragma unroll
            for (int s = 0; s < 4; ++s) {
                if (s <= slim) {
                    bf16x8 bp = *(const bf16x8*)((const char*)Ps[w] +
                            nl * 272 + s * 64 + q * 16);
                    #pragma unroll
                    for (int dt = 0; dt < 4; ++dt) {
                        bf16x8 av = *(const bf16x8*)((const char*)Vs +
                                ((s * 4 + q) * 64 + dt * 16 + nl) * 16);
                        accO[qb][dt] = __builtin_amdgcn_mfma_f32_16x16x32_bf16(
                                av, bp, accO[qb][dt], 0, 0, 0);
                    }
                }
            }
        }
    }

    // epilogue: lane holds O^T[dh = dt*16+q*4+r][query]; 1/l in-lane.
    #pragma unroll
    for (int qb = 0; qb < 2; ++qb) {
        const float inv = 1.0f / l_i[qb];
        const int t = q0 + w * 32 + qb * 16 + nl;
        #pragma unroll
        for (int dt = 0; dt < 4; ++dt) {
            union { u16 u[4]; uint2 v; } pk;
            #pragma unroll
            for (int r = 0; r < 4; ++r) pk.u[r] = f2bf(accO[qb][dt][r] * inv);
            *(uint2*)(AO + ((size_t)(b * Tt + t)) * Dd + h * DH + dt * 16 + q * 4) = pk.v;
        }
    }
}

// ---------------------------------------------------------------------------
extern "C" void kernel_launch(void* const* d_in, const int* in_sizes, int n_in,
                              void* d_out, int out_size, void* d_ws, size_t ws_size,
                              hipStream_t stream) {
    const float* x_raw    = (const float*)d_in[0];
    // d_in[1] = causal mask (constant tril) — handled analytically, ignored.
    const float* Wqkv_raw = (const float*)d_in[2];
    const float* Wout_raw = (const float*)d_in[3];
    float* out = (float*)d_out;

    const size_t SZ = (size_t)Bb * Hh * Tt * DH;        // 8,388,608
    u16* ws = (u16*)d_ws;
    u16* Qw     = ws;                                   // SZ
    u16* Kw     = ws + SZ;                              // SZ
    u16* Vw     = ws + 2 * SZ;                          // SZ (dead after transpose)
    u16* Vt     = ws + 3 * SZ;                          // SZ
    u16* Wqkv_t = ws + 4 * SZ;                          // 3,145,728  [3072][1024]
    u16* Wout_t = Wqkv_t + (size_t)3 * Dd * Dd;         // 1,048,576  [1024][1024]
    u16* AO     = Vw;                                   // alias V (B,T,D) bf16
    u16* x_b    = (u16*)d_out;                          // x bf16 scratch in d_out

    convert_x<<<dim3(Mrows * Dd / 2048), 256, 0, stream>>>(x_raw, x_b);
    convert_transpose_w<<<dim3(3 * Dd / 64, Dd / 64), 256, 0, stream>>>(Wqkv_raw, Wqkv_t, 3 * Dd, Dd);
    convert_transpose_w<<<dim3(Dd / 64, Dd / 64),     256, 0, stream>>>(Wout_raw, Wout_t, Dd, Dd);

    gemm_mfma<0><<<dim3(3 * Dd / 128, Mrows / 128), 256, 0, stream>>>(x_b, Wqkv_t, Qw, Kw, Vw, nullptr);
    transpose_v<<<dim3(Tt / 64, Bb * Hh), 256, 0, stream>>>(Vw, Vt);
    attn_mfma  <<<dim3(Tt / 128, Bb * Hh), 256, 0, stream>>>(Qw, Kw, Vt, AO);
    gemm_mfma<1><<<dim3(Dd / 128, Mrows / 128), 256, 0, stream>>>(AO, Wout_t, nullptr, nullptr, nullptr, out);
}

// Round 7
// 365.981 us; speedup vs baseline: 1.2616x; 1.2616x over previous
//
#include <hip/hip_runtime.h>
#include <hip/hip_bf16.h>
#include <math.h>

// B=4, T=2048, D=1024, H=16, DH=64.  fp32 in / fp32 out, bf16 MFMA internal.
// out = softmax_causal((xWq)(xWk)^T / 8) (xWv) @ Wout

#define Bb 4
#define Tt 2048
#define Dd 1024
#define Hh 16
#define DH 64
#define Mrows (Bb*Tt)          // 8192
#define NEGBIG (-1.0e30f)

typedef unsigned short u16;
typedef __attribute__((ext_vector_type(8))) short bf16x8;
typedef __attribute__((ext_vector_type(4))) float f32x4;

__device__ __forceinline__ float bf2f(u16 u) {
    union { unsigned int i; float f; } v; v.i = ((unsigned int)u) << 16; return v.f;
}
__device__ __forceinline__ u16 f2bf(float f) {
    union { float f; unsigned int i; } v; v.f = f;
    unsigned int x = v.i;
    return (u16)((x + 0x7fffu + ((x >> 16) & 1u)) >> 16);      // RNE
}

__device__ __forceinline__ float exp2_(float x) {
#if __has_builtin(__builtin_amdgcn_exp2f)
    return __builtin_amdgcn_exp2f(x);      // v_exp_f32: D = 2^S0
#else
    return __expf(x * 0.69314718056f);
#endif
}

typedef __attribute__((address_space(1))) const void glob_cv;
typedef __attribute__((address_space(3))) void lds_v;
__device__ __forceinline__ void gl2lds16(const void* g, void* l) {
    __builtin_amdgcn_global_load_lds((glob_cv*)g, (lds_v*)l, 16, 0, 0);
}

// ---------------------------------------------------------------------------
// fp32 -> bf16 straight convert (x).  8 elems/thread, 16B stores.
// ---------------------------------------------------------------------------
__global__ __launch_bounds__(256) void convert_x(const float* __restrict__ src,
                                                 u16* __restrict__ dst) {
    const long i = ((long)blockIdx.x * 256 + threadIdx.x) * 8;
    float4 f0 = *(const float4*)(src + i);
    float4 f1 = *(const float4*)(src + i + 4);
    union { u16 u[8]; uint4 v; } o;
    o.u[0] = f2bf(f0.x); o.u[1] = f2bf(f0.y); o.u[2] = f2bf(f0.z); o.u[3] = f2bf(f0.w);
    o.u[4] = f2bf(f1.x); o.u[5] = f2bf(f1.y); o.u[6] = f2bf(f1.z); o.u[7] = f2bf(f1.w);
    *(uint4*)(dst + i) = o.v;
}

// ---------------------------------------------------------------------------
// fp32 W[K][N] -> bf16 Wt[N][K]  (transpose via padded LDS tile, coalesced).
// ---------------------------------------------------------------------------
__global__ __launch_bounds__(256) void convert_transpose_w(const float* __restrict__ W,
                                                           u16* __restrict__ Wt,
                                                           int N, int K) {
    __shared__ u16 tile[64][65];
    const int n0 = blockIdx.x * 64, k0 = blockIdx.y * 64;
    const int c = threadIdx.x & 63, r4 = threadIdx.x >> 6;
    #pragma unroll
    for (int p = 0; p < 16; ++p) {
        const int r = p * 4 + r4;
        tile[r][c] = f2bf(W[(size_t)(k0 + r) * N + n0 + c]);
    }
    __syncthreads();
    #pragma unroll
    for (int p = 0; p < 16; ++p) {
        const int r = p * 4 + r4;     // n index
        Wt[(size_t)(n0 + r) * K + k0 + c] = tile[c][r];
    }
}

// ---------------------------------------------------------------------------
// MFMA GEMM: C[M][N] = A[M][K] * Bt[N][K]^T, K=1024, BK=32, 128x128 tile,
// 4 waves (2x2), each 4x4 MFMA 16x16x32 tiles.  LDS layout [kblk][row][8].
// MODE 0: scatter Q(xlog2e/8)/K as (B,H,T,DH), V TRANSPOSED as (B,H,DH,T).
// MODE 1: fp32 out, row-major.
// ---------------------------------------------------------------------------
template <int MODE>
__global__ __launch_bounds__(256) void gemm_mfma(const u16* __restrict__ A,
                                                 const u16* __restrict__ Bt,
                                                 u16* __restrict__ Qo,
                                                 u16* __restrict__ Ko,
                                                 u16* __restrict__ Vo,
                                                 float* __restrict__ Out) {
    __shared__ u16 As[4 * 128 * 8];      // [qb 0..3][row 0..127][8]
    __shared__ u16 Bs[4 * 128 * 8];
    const int tid  = threadIdx.x;
    const int lane = tid & 63, w = tid >> 6;
    const int ml   = lane & 15, q = lane >> 4;     // fragment row/col & quad
    const int wm   = w >> 1, wn = w & 1;
    const int m0 = blockIdx.y * 128, n0 = blockIdx.x * 128;

    f32x4 acc[4][4];
    #pragma unroll
    for (int i = 0; i < 4; ++i)
        #pragma unroll
        for (int j = 0; j < 4; ++j) acc[i][j] = (f32x4){0.f, 0.f, 0.f, 0.f};

    for (int k0 = 0; k0 < Dd; k0 += 32) {
        __syncthreads();
        #pragma unroll
        for (int it = 0; it < 2; ++it) {
            const int c = it * 256 + tid;          // chunk 0..511
            const int row = c & 127, qb = c >> 7;  // LDS off = c*16
            gl2lds16(A  + (size_t)(m0 + row) * Dd + k0 + qb * 8, (char*)As + c * 16);
            gl2lds16(Bt + (size_t)(n0 + row) * Dd + k0 + qb * 8, (char*)Bs + c * 16);
        }
        __syncthreads();

        bf16x8 af[4], bfr[4];
        #pragma unroll
        for (int i = 0; i < 4; ++i)
            af[i] = *(const bf16x8*)((const char*)As + (q * 128 + wm * 64 + i * 16 + ml) * 16);
        #pragma unroll
        for (int j = 0; j < 4; ++j)
            bfr[j] = *(const bf16x8*)((const char*)Bs + (q * 128 + wn * 64 + j * 16 + ml) * 16);
        #pragma unroll
        for (int i = 0; i < 4; ++i)
            #pragma unroll
            for (int j = 0; j < 4; ++j)
                acc[i][j] = __builtin_amdgcn_mfma_f32_16x16x32_bf16(af[i], bfr[j], acc[i][j], 0, 0, 0);
    }

    // epilogue: C/D layout col=lane&15, row=quad*4+reg
    #pragma unroll
    for (int i = 0; i < 4; ++i) {
        #pragma unroll
        for (int j = 0; j < 4; ++j) {
            #pragma unroll
            for (int r = 0; r < 4; ++r) {
                const int m = m0 + wm * 64 + i * 16 + q * 4 + r;
                const int n = n0 + wn * 64 + j * 16 + ml;
                if (MODE == 0) {
                    const int bb = m >> 11, t = m & 2047;
                    const int s = n >> 10, rem = n & 1023, h = rem >> 6, dh = rem & 63;
                    const int bhn = bb * Hh + h;
                    float v = acc[i][j][r];
                    // Q: fold 1/sqrt(DH) * log2(e) -> attention uses v_exp_f32
                    if (s == 0) v *= 0.125f * 1.44269504089f;
                    if (s == 2) {
                        // V stored transposed: [bh][dh][t]
                        Vo[((size_t)bhn * DH + dh) * Tt + t] = f2bf(v);
                    } else {
                        u16* dst = (s == 0) ? Qo : Ko;
                        dst[((size_t)bhn * Tt + t) * DH + dh] = f2bf(v);
                    }
                } else {
                    Out[(size_t)m * Dd + n] = acc[i][j][r];
                }
            }
        }
    }
}

// ---------------------------------------------------------------------------
// MFMA flash attention, S^T formulation, causal-pair load balancing.
// Grid (8, BH): block processes q-tiles {i, 15-i} sequentially -> every block
// does exactly 17 K-iterations (no tail imbalance).
// Wave owns 32 queries (2x16); Q fragments in registers (per phase).
// Branch-free inner loop (R6's runtime tile-skipping regressed: exec-mask
// branches around MFMAs defeated pipelining — reverted).
// ---------------------------------------------------------------------------
__global__ __launch_bounds__(256) void attn_mfma(const u16* __restrict__ Q,
                                                 const u16* __restrict__ K,
                                                 const u16* __restrict__ Vt,
                                                 u16* __restrict__ AO) {
    __shared__ u16 Ks[8 * 128 * 8];      // [dhb 0..7][key  0..127][8]   16 KB
    __shared__ u16 Vs[16 * 64 * 8];      // [kb 0..15][dh 0..63][8]      16 KB
    __shared__ u16 Ps[4][16 * 136];      // per-wave [query 16][128+8 pad] 17 KB

    const int tid  = threadIdx.x;
    const int lane = tid & 63, w = tid >> 6;
    const int nl   = lane & 15, q = lane >> 4;
    const int bh = blockIdx.y, b = bh >> 4, h = bh & 15;
    const size_t kbase = (size_t)bh * Tt * DH;
    const size_t vbase = (size_t)bh * DH * Tt;

    for (int phase = 0; phase < 2; ++phase) {
        const int qt = phase ? (15 - (int)blockIdx.x) : (int)blockIdx.x;
        const int q0 = qt * 128;

        // Q fragments in registers: qf[qb][s] = Q[qrow][(s*4+q)*8 .. +7]
        bf16x8 qf[2][2];
        #pragma unroll
        for (int qb = 0; qb < 2; ++qb)
            #pragma unroll
            for (int s = 0; s < 2; ++s)
                qf[qb][s] = *(const bf16x8*)(Q + kbase +
                        (size_t)(q0 + w * 32 + qb * 16 + nl) * DH + (s * 4 + q) * 8);

        float m_i[2] = {NEGBIG, NEGBIG};
        float l_i[2] = {0.f, 0.f};
        f32x4 accO[2][4];
        #pragma unroll
        for (int qb = 0; qb < 2; ++qb)
            #pragma unroll
            for (int dt = 0; dt < 4; ++dt) accO[qb][dt] = (f32x4){0.f, 0.f, 0.f, 0.f};

        for (int j0 = 0; j0 <= q0; j0 += 128) {
            __syncthreads();
            #pragma unroll
            for (int it = 0; it < 4; ++it) {
                const int c = it * 256 + tid;
                gl2lds16(K + kbase + (size_t)(j0 + (c & 127)) * DH + (c >> 7) * 8,
                         (char*)Ks + c * 16);
            }
            #pragma unroll
            for (int it = 0; it < 4; ++it) {
                const int c = it * 256 + tid;
                gl2lds16(Vt + vbase + (size_t)(c & 63) * Tt + j0 + (c >> 6) * 8,
                         (char*)Vs + c * 16);
            }
            __syncthreads();

            const bool diag = (j0 == q0);

            #pragma unroll
            for (int qb = 0; qb < 2; ++qb) {
                const int qrow = w * 32 + qb * 16 + nl;    // block-local query

                // S^T: lane holds keys (kt*16 + q*4 + r) for query qrow
                f32x4 accst[8];
                #pragma unroll
                for (int kt = 0; kt < 8; ++kt) accst[kt] = (f32x4){0.f, 0.f, 0.f, 0.f};
                #pragma unroll
                for (int s = 0; s < 2; ++s) {
                    #pragma unroll
                    for (int kt = 0; kt < 8; ++kt) {
                        bf16x8 ak = *(const bf16x8*)((const char*)Ks +
                                ((s * 4 + q) * 128 + kt * 16 + nl) * 16);
                        accst[kt] = __builtin_amdgcn_mfma_f32_16x16x32_bf16(
                                ak, qf[qb][s], accst[kt], 0, 0, 0);
                    }
                }

                // causal mask (diagonal 128-block only)
                if (diag) {
                    #pragma unroll
                    for (int kt = 0; kt < 8; ++kt)
                        #pragma unroll
                        for (int r = 0; r < 4; ++r)
                            if (kt * 16 + q * 4 + r > qrow) accst[kt][r] = NEGBIG;
                }

                // stats: in-register reduce over 32 keys + 2 shuffles
                float mx = NEGBIG;
                #pragma unroll
                for (int kt = 0; kt < 8; ++kt) {
                    float a0 = fmaxf(accst[kt][0], accst[kt][1]);
                    float a1 = fmaxf(accst[kt][2], accst[kt][3]);
                    mx = fmaxf(mx, fmaxf(a0, a1));
                }
                mx = fmaxf(mx, __shfl_xor(mx, 16, 64));
                mx = fmaxf(mx, __shfl_xor(mx, 32, 64));
                const float nm    = fmaxf(m_i[qb], mx);
                const float alpha = exp2_(m_i[qb] - nm);
                m_i[qb] = nm;

                float rs = 0.f;
                #pragma unroll
                for (int kt = 0; kt < 8; ++kt) {
                    union { u16 u[4]; uint2 v; } pk;
                    #pragma unroll
                    for (int r = 0; r < 4; ++r) {
                        const float p = exp2_(accst[kt][r] - nm);
                        rs += p;
                        pk.u[r] = f2bf(p);
                    }
                    *(uint2*)((char*)Ps[w] + nl * 272 + kt * 32 + q * 8) = pk.v;
                }
                rs += __shfl_xor(rs, 16, 64);
                rs += __shfl_xor(rs, 32, 64);
                l_i[qb] = l_i[qb] * alpha + rs;

                // rescale O^T (query on lane -> in-lane alpha)
                #pragma unroll
                for (int dt = 0; dt < 4; ++dt)
                    #pragma unroll
                    for (int r = 0; r < 4; ++r) accO[qb][dt][r] *= alpha;

                // O^T += V^T · P^T   (a = Vt rows, b = Ps rows)
                #pragma unroll
                for (int s = 0; s < 4; ++s) {
                    bf16x8 bp = *(const bf16x8*)((const char*)Ps[w] +
                            nl * 272 + s * 64 + q * 16);
                    #pragma unroll
                    for (int dt = 0; dt < 4; ++dt) {
                        bf16x8 av = *(const bf16x8*)((const char*)Vs +
                                ((s * 4 + q) * 64 + dt * 16 + nl) * 16);
                        accO[qb][dt] = __builtin_amdgcn_mfma_f32_16x16x32_bf16(
                                av, bp, accO[qb][dt], 0, 0, 0);
                    }
                }
            }
        }

        // epilogue: lane holds O^T[dh = dt*16+q*4+r][query]; 1/l in-lane.
        #pragma unroll
        for (int qb = 0; qb < 2; ++qb) {
            const float inv = 1.0f / l_i[qb];
            const int t = q0 + w * 32 + qb * 16 + nl;
            #pragma unroll
            for (int dt = 0; dt < 4; ++dt) {
                union { u16 u[4]; uint2 v; } pk;
                #pragma unroll
                for (int r = 0; r < 4; ++r) pk.u[r] = f2bf(accO[qb][dt][r] * inv);
                *(uint2*)(AO + ((size_t)(b * Tt + t)) * Dd + h * DH + dt * 16 + q * 4) = pk.v;
            }
        }
    }
}

// ---------------------------------------------------------------------------
extern "C" void kernel_launch(void* const* d_in, const int* in_sizes, int n_in,
                              void* d_out, int out_size, void* d_ws, size_t ws_size,
                              hipStream_t stream) {
    const float* x_raw    = (const float*)d_in[0];
    // d_in[1] = causal mask (constant tril) — handled analytically, ignored.
    const float* Wqkv_raw = (const float*)d_in[2];
    const float* Wout_raw = (const float*)d_in[3];
    float* out = (float*)d_out;

    const size_t SZ = (size_t)Bb * Hh * Tt * DH;        // 8,388,608
    u16* ws = (u16*)d_ws;
    u16* Qw     = ws;                                   // SZ
    u16* Kw     = ws + SZ;                              // SZ
    u16* Vt     = ws + 2 * SZ;                          // SZ, [bh][dh][t]
    u16* AO     = ws + 3 * SZ;                          // SZ, (B,T,D) bf16
    u16* Wqkv_t = ws + 4 * SZ;                          // 3,145,728  [3072][1024]
    u16* Wout_t = Wqkv_t + (size_t)3 * Dd * Dd;         // 1,048,576  [1024][1024]
    u16* x_b    = (u16*)d_out;                          // x bf16 scratch in d_out

    convert_x<<<dim3(Mrows * Dd / 2048), 256, 0, stream>>>(x_raw, x_b);
    convert_transpose_w<<<dim3(3 * Dd / 64, Dd / 64), 256, 0, stream>>>(Wqkv_raw, Wqkv_t, 3 * Dd, Dd);
    convert_transpose_w<<<dim3(Dd / 64, Dd / 64),     256, 0, stream>>>(Wout_raw, Wout_t, Dd, Dd);

    gemm_mfma<0><<<dim3(3 * Dd / 128, Mrows / 128), 256, 0, stream>>>(x_b, Wqkv_t, Qw, Kw, Vt, nullptr);
    attn_mfma  <<<dim3(Tt / 256, Bb * Hh), 256, 0, stream>>>(Qw, Kw, Vt, AO);
    gemm_mfma<1><<<dim3(Dd / 128, Mrows / 128), 256, 0, stream>>>(AO, Wout_t, nullptr, nullptr, nullptr, out);
}

// Round 8
// 356.056 us; speedup vs baseline: 1.2968x; 1.0279x over previous
//
#include <hip/hip_runtime.h>
#include <hip/hip_bf16.h>
#include <math.h>

// B=4, T=2048, D=1024, H=16, DH=64.  fp32 in / fp32 out, bf16 MFMA internal.
// out = softmax_causal((xWq)(xWk)^T / 8) (xWv) @ Wout

#define Bb 4
#define Tt 2048
#define Dd 1024
#define Hh 16
#define DH 64
#define Mrows (Bb*Tt)          // 8192
#define NEGBIG (-1.0e30f)

typedef unsigned short u16;
typedef __attribute__((ext_vector_type(8))) short bf16x8;
typedef __attribute__((ext_vector_type(4))) float f32x4;

__device__ __forceinline__ float bf2f(u16 u) {
    union { unsigned int i; float f; } v; v.i = ((unsigned int)u) << 16; return v.f;
}
__device__ __forceinline__ u16 f2bf(float f) {
    union { float f; unsigned int i; } v; v.f = f;
    unsigned int x = v.i;
    return (u16)((x + 0x7fffu + ((x >> 16) & 1u)) >> 16);      // RNE
}

__device__ __forceinline__ float exp2_(float x) {
#if __has_builtin(__builtin_amdgcn_exp2f)
    return __builtin_amdgcn_exp2f(x);      // v_exp_f32: D = 2^S0
#else
    return __expf(x * 0.69314718056f);
#endif
}

typedef __attribute__((address_space(1))) const void glob_cv;
typedef __attribute__((address_space(3))) void lds_v;
__device__ __forceinline__ void gl2lds16(const void* g, void* l) {
    __builtin_amdgcn_global_load_lds((glob_cv*)g, (lds_v*)l, 16, 0, 0);
}

// ---------------------------------------------------------------------------
// fp32 -> bf16 straight convert (x).  8 elems/thread, 16B stores.
// ---------------------------------------------------------------------------
__global__ __launch_bounds__(256) void convert_x(const float* __restrict__ src,
                                                 u16* __restrict__ dst) {
    const long i = ((long)blockIdx.x * 256 + threadIdx.x) * 8;
    float4 f0 = *(const float4*)(src + i);
    float4 f1 = *(const float4*)(src + i + 4);
    union { u16 u[8]; uint4 v; } o;
    o.u[0] = f2bf(f0.x); o.u[1] = f2bf(f0.y); o.u[2] = f2bf(f0.z); o.u[3] = f2bf(f0.w);
    o.u[4] = f2bf(f1.x); o.u[5] = f2bf(f1.y); o.u[6] = f2bf(f1.z); o.u[7] = f2bf(f1.w);
    *(uint4*)(dst + i) = o.v;
}

// ---------------------------------------------------------------------------
// fp32 W[K][N] -> bf16 Wt[N][K]  (transpose via padded LDS tile, coalesced).
// ---------------------------------------------------------------------------
__global__ __launch_bounds__(256) void convert_transpose_w(const float* __restrict__ W,
                                                           u16* __restrict__ Wt,
                                                           int N, int K) {
    __shared__ u16 tile[64][65];
    const int n0 = blockIdx.x * 64, k0 = blockIdx.y * 64;
    const int c = threadIdx.x & 63, r4 = threadIdx.x >> 6;
    #pragma unroll
    for (int p = 0; p < 16; ++p) {
        const int r = p * 4 + r4;
        tile[r][c] = f2bf(W[(size_t)(k0 + r) * N + n0 + c]);
    }
    __syncthreads();
    #pragma unroll
    for (int p = 0; p < 16; ++p) {
        const int r = p * 4 + r4;     // n index
        Wt[(size_t)(n0 + r) * K + k0 + c] = tile[c][r];
    }
}

// ---------------------------------------------------------------------------
// MFMA GEMM: C[M][N] = A[M][K] * Bt[N][K]^T, K=1024, BK=64, 128x128 tile,
// 4 waves (2x2), each 4x4 MFMA 16x16x32 tiles, 2 k-subs per iter.
// TRANSPOSED accumulation: acc = mfma(a=B_frag, b=A_frag) -> D^T, so
// lane&15 = m, quad*4+reg = n (4 consecutive n per lane -> wide stores).
// MODE 0: scatter Q(xlog2e/8)/K as (B,H,T,DH) via uint2; V as (B,H,DH,T)
//         with t-on-lanes (coalesced).  MODE 1: fp32 out via float4.
// ---------------------------------------------------------------------------
template <int MODE>
__global__ __launch_bounds__(256) void gemm_mfma(const u16* __restrict__ A,
                                                 const u16* __restrict__ Bt,
                                                 u16* __restrict__ Qo,
                                                 u16* __restrict__ Ko,
                                                 u16* __restrict__ Vo,
                                                 float* __restrict__ Out) {
    __shared__ u16 As[8 * 128 * 8];      // [qb 0..7][row 0..127][8]  16 KB
    __shared__ u16 Bs[8 * 128 * 8];      // 16 KB
    const int tid  = threadIdx.x;
    const int lane = tid & 63, w = tid >> 6;
    const int ml   = lane & 15, q = lane >> 4;
    const int wm   = w >> 1, wn = w & 1;
    const int m0 = blockIdx.y * 128, n0 = blockIdx.x * 128;

    f32x4 acc[4][4];
    #pragma unroll
    for (int i = 0; i < 4; ++i)
        #pragma unroll
        for (int j = 0; j < 4; ++j) acc[i][j] = (f32x4){0.f, 0.f, 0.f, 0.f};

    for (int k0 = 0; k0 < Dd; k0 += 64) {
        __syncthreads();
        #pragma unroll
        for (int it = 0; it < 4; ++it) {
            const int c = it * 256 + tid;          // chunk 0..1023
            const int row = c & 127, qb = c >> 7;  // LDS off = c*16
            gl2lds16(A  + (size_t)(m0 + row) * Dd + k0 + qb * 8, (char*)As + c * 16);
            gl2lds16(Bt + (size_t)(n0 + row) * Dd + k0 + qb * 8, (char*)Bs + c * 16);
        }
        __syncthreads();

        #pragma unroll
        for (int ks = 0; ks < 2; ++ks) {
            bf16x8 af[4], bfr[4];
            #pragma unroll
            for (int i = 0; i < 4; ++i)
                af[i] = *(const bf16x8*)((const char*)As +
                        (((ks * 4 + q) * 128) + wm * 64 + i * 16 + ml) * 16);
            #pragma unroll
            for (int j = 0; j < 4; ++j)
                bfr[j] = *(const bf16x8*)((const char*)Bs +
                        (((ks * 4 + q) * 128) + wn * 64 + j * 16 + ml) * 16);
            #pragma unroll
            for (int i = 0; i < 4; ++i)
                #pragma unroll
                for (int j = 0; j < 4; ++j)
                    acc[i][j] = __builtin_amdgcn_mfma_f32_16x16x32_bf16(
                            bfr[j], af[i], acc[i][j], 0, 0, 0);   // D^T
        }
    }

    // epilogue (D^T): m = m0+wm*64+i*16+ml ; n = n0+wn*64+j*16+q*4+r
    if (MODE == 0) {
        const int s = n0 >> 10;                    // 0=q 1=k 2=v, block-uniform
        #pragma unroll
        for (int i = 0; i < 4; ++i) {
            const int m  = m0 + wm * 64 + i * 16 + ml;
            const int bb = m >> 11, t = m & 2047;
            #pragma unroll
            for (int j = 0; j < 4; ++j) {
                const int nn = wn * 64 + j * 16 + q * 4;   // n - n0
                const int dh = nn & 63;
                const int h  = ((n0 & 1023) + nn) >> 6;
                const int bhn = bb * Hh + h;
                if (s == 2) {
                    // V^T [bh][dh][t]: lanes (ml) cover consecutive t
                    #pragma unroll
                    for (int r = 0; r < 4; ++r)
                        Vo[((size_t)bhn * DH + dh + r) * Tt + t] = f2bf(acc[i][j][r]);
                } else {
                    union { u16 u[4]; uint2 v; } pk;
                    #pragma unroll
                    for (int r = 0; r < 4; ++r) {
                        float v = acc[i][j][r];
                        if (s == 0) v *= 0.125f * 1.44269504089f;  // /sqrt(DH)*log2e
                        pk.u[r] = f2bf(v);
                    }
                    u16* dst = (s == 0) ? Qo : Ko;
                    *(uint2*)(dst + ((size_t)bhn * Tt + t) * DH + dh) = pk.v;
                }
            }
        }
    } else {
        #pragma unroll
        for (int i = 0; i < 4; ++i) {
            const int m = m0 + wm * 64 + i * 16 + ml;
            #pragma unroll
            for (int j = 0; j < 4; ++j) {
                const int n = n0 + wn * 64 + j * 16 + q * 4;
                float4 st = {acc[i][j][0], acc[i][j][1], acc[i][j][2], acc[i][j][3]};
                *(float4*)(Out + (size_t)m * Dd + n) = st;
            }
        }
    }
}

// ---------------------------------------------------------------------------
// MFMA flash attention, S^T formulation, causal-pair load balancing.
// Grid (8, BH): block processes q-tiles {i, 15-i} -> exactly 17 K-iters each.
// Wave owns 32 queries (2x16); Q fragments in registers (per phase).
// ---------------------------------------------------------------------------
__global__ __launch_bounds__(256) void attn_mfma(const u16* __restrict__ Q,
                                                 const u16* __restrict__ K,
                                                 const u16* __restrict__ Vt,
                                                 u16* __restrict__ AO) {
    __shared__ u16 Ks[8 * 128 * 8];      // [dhb 0..7][key  0..127][8]   16 KB
    __shared__ u16 Vs[16 * 64 * 8];      // [kb 0..15][dh 0..63][8]      16 KB
    __shared__ u16 Ps[4][16 * 136];      // per-wave [query 16][128+8 pad] 17 KB

    const int tid  = threadIdx.x;
    const int lane = tid & 63, w = tid >> 6;
    const int nl   = lane & 15, q = lane >> 4;
    const int bh = blockIdx.y, b = bh >> 4, h = bh & 15;
    const size_t kbase = (size_t)bh * Tt * DH;
    const size_t vbase = (size_t)bh * DH * Tt;

    for (int phase = 0; phase < 2; ++phase) {
        const int qt = phase ? (15 - (int)blockIdx.x) : (int)blockIdx.x;
        const int q0 = qt * 128;

        bf16x8 qf[2][2];
        #pragma unroll
        for (int qb = 0; qb < 2; ++qb)
            #pragma unroll
            for (int s = 0; s < 2; ++s)
                qf[qb][s] = *(const bf16x8*)(Q + kbase +
                        (size_t)(q0 + w * 32 + qb * 16 + nl) * DH + (s * 4 + q) * 8);

        float m_i[2] = {NEGBIG, NEGBIG};
        float l_i[2] = {0.f, 0.f};
        f32x4 accO[2][4];
        #pragma unroll
        for (int qb = 0; qb < 2; ++qb)
            #pragma unroll
            for (int dt = 0; dt < 4; ++dt) accO[qb][dt] = (f32x4){0.f, 0.f, 0.f, 0.f};

        for (int j0 = 0; j0 <= q0; j0 += 128) {
            __syncthreads();
            #pragma unroll
            for (int it = 0; it < 4; ++it) {
                const int c = it * 256 + tid;
                gl2lds16(K + kbase + (size_t)(j0 + (c & 127)) * DH + (c >> 7) * 8,
                         (char*)Ks + c * 16);
            }
            #pragma unroll
            for (int it = 0; it < 4; ++it) {
                const int c = it * 256 + tid;
                gl2lds16(Vt + vbase + (size_t)(c & 63) * Tt + j0 + (c >> 6) * 8,
                         (char*)Vs + c * 16);
            }
            __syncthreads();

            const bool diag = (j0 == q0);

            #pragma unroll
            for (int qb = 0; qb < 2; ++qb) {
                const int qrow = w * 32 + qb * 16 + nl;

                f32x4 accst[8];
                #pragma unroll
                for (int kt = 0; kt < 8; ++kt) accst[kt] = (f32x4){0.f, 0.f, 0.f, 0.f};
                #pragma unroll
                for (int s = 0; s < 2; ++s) {
                    #pragma unroll
                    for (int kt = 0; kt < 8; ++kt) {
                        bf16x8 ak = *(const bf16x8*)((const char*)Ks +
                                ((s * 4 + q) * 128 + kt * 16 + nl) * 16);
                        accst[kt] = __builtin_amdgcn_mfma_f32_16x16x32_bf16(
                                ak, qf[qb][s], accst[kt], 0, 0, 0);
                    }
                }

                if (diag) {
                    #pragma unroll
                    for (int kt = 0; kt < 8; ++kt)
                        #pragma unroll
                        for (int r = 0; r < 4; ++r)
                            if (kt * 16 + q * 4 + r > qrow) accst[kt][r] = NEGBIG;
                }

                float mx = NEGBIG;
                #pragma unroll
                for (int kt = 0; kt < 8; ++kt) {
                    float a0 = fmaxf(accst[kt][0], accst[kt][1]);
                    float a1 = fmaxf(accst[kt][2], accst[kt][3]);
                    mx = fmaxf(mx, fmaxf(a0, a1));
                }
                mx = fmaxf(mx, __shfl_xor(mx, 16, 64));
                mx = fmaxf(mx, __shfl_xor(mx, 32, 64));
                const float nm    = fmaxf(m_i[qb], mx);
                const float alpha = exp2_(m_i[qb] - nm);
                m_i[qb] = nm;

                float rs = 0.f;
                #pragma unroll
                for (int kt = 0; kt < 8; ++kt) {
                    union { u16 u[4]; uint2 v; } pk;
                    #pragma unroll
                    for (int r = 0; r < 4; ++r) {
                        const float p = exp2_(accst[kt][r] - nm);
                        rs += p;
                        pk.u[r] = f2bf(p);
                    }
                    *(uint2*)((char*)Ps[w] + nl * 272 + kt * 32 + q * 8) = pk.v;
                }
                rs += __shfl_xor(rs, 16, 64);
                rs += __shfl_xor(rs, 32, 64);
                l_i[qb] = l_i[qb] * alpha + rs;

                #pragma unroll
                for (int dt = 0; dt < 4; ++dt)
                    #pragma unroll
                    for (int r = 0; r < 4; ++r) accO[qb][dt][r] *= alpha;

                #pragma unroll
                for (int s = 0; s < 4; ++s) {
                    bf16x8 bp = *(const bf16x8*)((const char*)Ps[w] +
                            nl * 272 + s * 64 + q * 16);
                    #pragma unroll
                    for (int dt = 0; dt < 4; ++dt) {
                        bf16x8 av = *(const bf16x8*)((const char*)Vs +
                                ((s * 4 + q) * 64 + dt * 16 + nl) * 16);
                        accO[qb][dt] = __builtin_amdgcn_mfma_f32_16x16x32_bf16(
                                av, bp, accO[qb][dt], 0, 0, 0);
                    }
                }
            }
        }

        #pragma unroll
        for (int qb = 0; qb < 2; ++qb) {
            const float inv = 1.0f / l_i[qb];
            const int t = q0 + w * 32 + qb * 16 + nl;
            #pragma unroll
            for (int dt = 0; dt < 4; ++dt) {
                union { u16 u[4]; uint2 v; } pk;
                #pragma unroll
                for (int r = 0; r < 4; ++r) pk.u[r] = f2bf(accO[qb][dt][r] * inv);
                *(uint2*)(AO + ((size_t)(b * Tt + t)) * Dd + h * DH + dt * 16 + q * 4) = pk.v;
            }
        }
    }
}

// ---------------------------------------------------------------------------
extern "C" void kernel_launch(void* const* d_in, const int* in_sizes, int n_in,
                              void* d_out, int out_size, void* d_ws, size_t ws_size,
                              hipStream_t stream) {
    const float* x_raw    = (const float*)d_in[0];
    // d_in[1] = causal mask (constant tril) — handled analytically, ignored.
    const float* Wqkv_raw = (const float*)d_in[2];
    const float* Wout_raw = (const float*)d_in[3];
    float* out = (float*)d_out;

    const size_t SZ = (size_t)Bb * Hh * Tt * DH;        // 8,388,608
    u16* ws = (u16*)d_ws;
    u16* Qw     = ws;                                   // SZ
    u16* Kw     = ws + SZ;                              // SZ
    u16* Vt     = ws + 2 * SZ;                          // SZ, [bh][dh][t]
    u16* AO     = ws + 3 * SZ;                          // SZ, (B,T,D) bf16
    u16* Wqkv_t = ws + 4 * SZ;                          // 3,145,728  [3072][1024]
    u16* Wout_t = Wqkv_t + (size_t)3 * Dd * Dd;         // 1,048,576  [1024][1024]
    u16* x_b    = (u16*)d_out;                          // x bf16 scratch in d_out

    convert_x<<<dim3(Mrows * Dd / 2048), 256, 0, stream>>>(x_raw, x_b);
    convert_transpose_w<<<dim3(3 * Dd / 64, Dd / 64), 256, 0, stream>>>(Wqkv_raw, Wqkv_t, 3 * Dd, Dd);
    convert_transpose_w<<<dim3(Dd / 64, Dd / 64),     256, 0, stream>>>(Wout_raw, Wout_t, Dd, Dd);

    gemm_mfma<0><<<dim3(3 * Dd / 128, Mrows / 128), 256, 0, stream>>>(x_b, Wqkv_t, Qw, Kw, Vt, nullptr);
    attn_mfma  <<<dim3(Tt / 256, Bb * Hh), 256, 0, stream>>>(Qw, Kw, Vt, AO);
    gemm_mfma<1><<<dim3(Dd / 128, Mrows / 128), 256, 0, stream>>>(AO, Wout_t, nullptr, nullptr, nullptr, out);
}